// Round 2
// 344.415 us; speedup vs baseline: 1.1660x; 1.1660x over previous
//
#include <hip/hip_runtime.h>

// ESSAttn bf16-MFMA version. b=8, C=64, H=W=256 (N=65536), fp32 in/out.
// Math (exact refactor of reference):
//   out[b,n,d] = x_col(n)@wvln[d,:] + bias2[d] + w_row[n] * sum_c q2[n,c]*kvw[b][c][d]
//   kvw[c][d]  = inv_k[c] * sum_e kvu[c][e]*w_ln[d][e],  inv_k = 1/(256*max(sqrt(ksq_c),1e-12))
//   kvu[c][e]  = sum_n k2t[n,c]*v[n,e],  ksq_c = sum_n k2t^2
//   k2t = (k-mean_c(k))^2/(k2s+1e-7),  q2 = (q-mean)^2, w_row folds q2 normalizations.
// This round: x is read via coalesced float4 -> LDS staging (stride-66 pad: transposed
// b32 frag reads are balanced 2-way, free) instead of 256KB-strided scalar dwords;
// k1 register-prefetches the next tile across the barrier; k2 parallelized 4x + vectorized.
// (Resubmission of round-1 kernel: previous run died to a container flake, no counters.)

typedef unsigned short u16;
typedef unsigned int u32;
typedef short bf16x8_t __attribute__((ext_vector_type(8)));
typedef float f32x4_t __attribute__((ext_vector_type(4)));

#define NN 65536
#define G1 96
#define STK 68   // bf16 LDS tile stride (elements)
#define STO 72   // fp32 out-transpose stride
#define SXS 66   // fp32 x-tile LDS stride (66: quad c-offset 8 -> 528 % 32 = 16 -> 2-way free)

static __device__ __forceinline__ u16 f2bf(float f) {
    union { float f; u32 u; } v; v.f = f;
    u32 r = v.u + 0x7FFFu + ((v.u >> 16) & 1u);
    return (u16)(r >> 16);
}
static __device__ __forceinline__ u32 pack2(float a, float b) {
    return (u32)f2bf(a) | ((u32)f2bf(b) << 16);
}

// ---------------- K0: cast weights to bf16; wvln = w_ln @ w_v; bias2 = w_ln@b_v + b_ln
__global__ void k0_prep(const float* __restrict__ w_qkv, const float* __restrict__ b_qkv,
                        const float* __restrict__ w_ln, const float* __restrict__ b_ln,
                        u16* __restrict__ w_kv_bf, u16* __restrict__ w_q_bf,
                        u16* __restrict__ wvln_bf, float* __restrict__ bias2) {
    int idx = blockIdx.x * 256 + threadIdx.x;
    if (idx < 8192) {                       // rows 64..191 of w_qkv = [w_k | w_v]
        w_kv_bf[idx] = f2bf(w_qkv[4096 + idx]);
    } else if (idx < 12288) {               // rows 0..63 = w_q
        w_q_bf[idx - 8192] = f2bf(w_qkv[idx - 8192]);
    } else if (idx < 16384) {
        int i = idx - 12288; int d = i >> 6, c = i & 63;
        float s = 0.f;
        #pragma unroll 8
        for (int e = 0; e < 64; ++e)
            s += w_ln[d * 64 + e] * w_qkv[(128 + e) * 64 + c];
        wvln_bf[i] = f2bf(s);
    } else if (idx < 16448) {
        int d = idx - 16384;
        float s = b_ln[d];
        #pragma unroll 8
        for (int e = 0; e < 64; ++e)
            s += w_ln[d * 64 + e] * b_qkv[128 + e];
        bias2[d] = s;
    }
}

// ---------------- K1: per (g,b): loop n-tiles of 64; coalesced x staging + reg prefetch;
// MFMA k|v GEMM; shuffle stats; LDS-transpose k2t,v to bf16; MFMA kvu accumulation;
// flush per-block partials.
__global__ __launch_bounds__(256) void k1_kv(const float* __restrict__ x,
        const u16* __restrict__ w_kv_bf, const float* __restrict__ b_qkv,
        float* __restrict__ kvu_part, float* __restrict__ ksq_part) {
    __shared__ float xs[64 * SXS]; // x tile fp32: [c][n]
    __shared__ u16 kt[64 * STK];   // k2t^T: [c][n] bf16
    __shared__ u16 vt[64 * STK];   // v^T:   [e][n] bf16
    __shared__ float ksq_red[4][64];
    const int tid = threadIdx.x;
    const int w = tid >> 6, lane = tid & 63, q = lane >> 4, l15 = lane & 15;
    const int b = blockIdx.y, g = blockIdx.x;
    const float* xb = x + (size_t)b * 64 * NN;
    const int sc = tid >> 4;          // staging channel (+16*i), 16 lanes per row
    const int sn = (tid & 15) << 2;   // staging n offset (float4)
    const float* xg = xb + (size_t)sc * NN + sn;

    float bias[8];
    #pragma unroll
    for (int t8 = 0; t8 < 8; ++t8) bias[t8] = b_qkv[64 + 16 * t8 + l15];

    f32x4_t accK[4];
    #pragma unroll
    for (int et = 0; et < 4; ++et) accK[et] = (f32x4_t){0.f, 0.f, 0.f, 0.f};
    float ksq_acc[4] = {0.f, 0.f, 0.f, 0.f};

    // prefetch first tile into registers
    float4 pf[4];
    #pragma unroll
    for (int i = 0; i < 4; ++i)
        pf[i] = *(const float4*)(xg + (size_t)(16 * i) * NN + g * 64);

    for (int t = g; t < NN / 64; t += G1) {
        // ---- commit prefetched x tile to LDS (coalesced source, 2-way-free writes)
        #pragma unroll
        for (int i = 0; i < 4; ++i) {
            int c = 16 * i + sc;
            *(float2*)&xs[c * SXS + sn]     = make_float2(pf[i].x, pf[i].y);
            *(float2*)&xs[c * SXS + sn + 2] = make_float2(pf[i].z, pf[i].w);
        }
        __syncthreads();
        // ---- issue next tile's loads; latency hides under GEMM/stats below
        if (t + G1 < NN / 64) {
            #pragma unroll
            for (int i = 0; i < 4; ++i)
                pf[i] = *(const float4*)(xg + (size_t)(16 * i) * NN + (t + G1) * 64);
        }
        // ---- GEMM A: D[n][dcol], dcol 0..63 = k, 64..127 = v (K = 64 channels)
        f32x4_t accA[8];
        #pragma unroll
        for (int t8 = 0; t8 < 8; ++t8)
            accA[t8] = (f32x4_t){bias[t8], bias[t8], bias[t8], bias[t8]};
        #pragma unroll
        for (int ks = 0; ks < 2; ++ks) {
            // A-frag: x^T[n][c] via transposed LDS reads (balanced 2-way banks)
            union { u16 u[8]; bf16x8_t v; } af;
            #pragma unroll
            for (int j = 0; j < 8; ++j)
                af.u[j] = f2bf(xs[(ks * 32 + q * 8 + j) * SXS + 16 * w + l15]);
            #pragma unroll
            for (int t8 = 0; t8 < 8; ++t8) {
                bf16x8_t bf = *(const bf16x8_t*)(w_kv_bf + (16 * t8 + l15) * 64 + ks * 32 + q * 8);
                accA[t8] = __builtin_amdgcn_mfma_f32_16x16x32_bf16(af.v, bf, accA[t8], 0, 0, 0);
            }
        }
        // ---- k stats per row (row = 4q + r): mean, 1/(k2s+eps) via 16-lane butterflies
        float mu[4], rin[4];
        #pragma unroll
        for (int r = 0; r < 4; ++r) {
            float a0 = accA[0][r], a1 = accA[1][r], a2 = accA[2][r], a3 = accA[3][r];
            float s1 = a0 + a1 + a2 + a3;
            float s2 = a0 * a0 + a1 * a1 + a2 * a2 + a3 * a3;
            #pragma unroll
            for (int m = 1; m <= 8; m <<= 1) {
                s1 += __shfl_xor(s1, m, 64);
                s2 += __shfl_xor(s2, m, 64);
            }
            mu[r] = s1 * 0.015625f;
            rin[r] = 1.f / (s2 - 64.f * mu[r] * mu[r] + 1e-7f);
        }
        // ---- k2t -> kt LDS (bf16), ksq accumulate; v -> vt LDS
        #pragma unroll
        for (int t4 = 0; t4 < 4; ++t4) {
            float t2v[4];
            #pragma unroll
            for (int r = 0; r < 4; ++r) {
                float d = accA[t4][r] - mu[r];
                float t2 = d * d * rin[r];
                t2v[r] = t2;
                ksq_acc[t4] += t2 * t2;
            }
            int base = (16 * t4 + l15) * STK + 16 * w + 4 * q;
            *(u32*)&kt[base] = pack2(t2v[0], t2v[1]);
            *(u32*)&kt[base + 2] = pack2(t2v[2], t2v[3]);
        }
        #pragma unroll
        for (int t4 = 0; t4 < 4; ++t4) {
            int base = (16 * t4 + l15) * STK + 16 * w + 4 * q;
            *(u32*)&vt[base] = pack2(accA[4 + t4][0], accA[4 + t4][1]);
            *(u32*)&vt[base + 2] = pack2(accA[4 + t4][2], accA[4 + t4][3]);
        }
        __syncthreads();
        // ---- kvu: D[c][e] += sum_n k2t[n][c]*v[n][e]; wave w owns c-tile w
        #pragma unroll
        for (int ks2 = 0; ks2 < 2; ++ks2) {
            union { bf16x8_t v; uint2 h[2]; } a2;
            const u16* ap = &kt[(16 * w + l15) * STK + ks2 * 32 + q * 8];
            a2.h[0] = *(const uint2*)ap;
            a2.h[1] = *(const uint2*)(ap + 4);
            #pragma unroll
            for (int et = 0; et < 4; ++et) {
                union { bf16x8_t v; uint2 h[2]; } b2;
                const u16* bp = &vt[(16 * et + l15) * STK + ks2 * 32 + q * 8];
                b2.h[0] = *(const uint2*)bp;
                b2.h[1] = *(const uint2*)(bp + 4);
                accK[et] = __builtin_amdgcn_mfma_f32_16x16x32_bf16(a2.v, b2.v, accK[et], 0, 0, 0);
            }
        }
        __syncthreads();
    }
    // ---- flush partials
    float* kp = kvu_part + (size_t)(b * G1 + g) * 4096;
    #pragma unroll
    for (int et = 0; et < 4; ++et)
        #pragma unroll
        for (int r = 0; r < 4; ++r)
            kp[(16 * w + 4 * q + r) * 64 + 16 * et + l15] = accK[et][r];
    #pragma unroll
    for (int t4 = 0; t4 < 4; ++t4) {
        float v = ksq_acc[t4];
        v += __shfl_xor(v, 16, 64);
        v += __shfl_xor(v, 32, 64);
        if (q == 0) ksq_red[w][16 * t4 + l15] = v;
    }
    __syncthreads();
    if (tid < 64)
        ksq_part[(size_t)(b * G1 + g) * 64 + tid] =
            ksq_red[0][tid] + ksq_red[1][tid] + ksq_red[2][tid] + ksq_red[3][tid];
}

// ---------------- K2: reduce partials over g; kvw_t[b][d][c] = bf16(inv_k[c]*sum_e kvu[c][e]*w_ln[d][e])
// 4x more blocks than before (grid 16x8), 8-deep ILP on the g-reduction, float4 dot products.
__global__ __launch_bounds__(256) void k2_kvw(const float* __restrict__ kvu_part,
        const float* __restrict__ ksq_part, const float* __restrict__ w_ln,
        u16* __restrict__ kvw_t) {
    __shared__ float wln_s[64 * 68];
    __shared__ float kvr[4 * 68];
    __shared__ float ksq_r[64];
    __shared__ float inv_k[4];
    const int tid = threadIdx.x;
    const int c0 = blockIdx.x * 4, b = blockIdx.y;
    #pragma unroll
    for (int lidx = 0; lidx < 16; ++lidx) {
        int idx = tid + 256 * lidx;
        wln_s[(idx >> 6) * 68 + (idx & 63)] = w_ln[idx];
    }
    {   // thread (cl = tid>>6, e = tid&63): sum kvu over g, 8 concurrent chains
        const int cl = tid >> 6, e = tid & 63;
        const float* p = kvu_part + (size_t)b * G1 * 4096 + (c0 + cl) * 64 + e;
        float s[8];
        #pragma unroll
        for (int k = 0; k < 8; ++k) s[k] = 0.f;
        for (int g = 0; g < G1; g += 8) {
            #pragma unroll
            for (int k = 0; k < 8; ++k) s[k] += p[(size_t)(g + k) * 4096];
        }
        kvr[cl * 68 + e] = ((s[0] + s[1]) + (s[2] + s[3])) + ((s[4] + s[5]) + (s[6] + s[7]));
    }
    if (tid < 64) {  // ksq reduce spread over 16 g-partials x 4 c
        const int cl = tid & 3, gp = tid >> 2;
        float s = 0.f;
        #pragma unroll
        for (int k = 0; k < 6; ++k)
            s += ksq_part[(size_t)(b * G1 + gp + 16 * k) * 64 + c0 + cl];
        ksq_r[tid] = s;
    }
    __syncthreads();
    if (tid < 4) {
        float s = 0.f;
        #pragma unroll
        for (int gp = 0; gp < 16; ++gp) s += ksq_r[gp * 4 + tid];
        inv_k[tid] = 1.f / (fmaxf(sqrtf(s), 1e-12f) * 256.f);
    }
    __syncthreads();
    {   // thread (d = tid>>2, cl = tid&3): 64-wide dot, vectorized
        const int d = tid >> 2, cl = tid & 3;
        float s = 0.f;
        #pragma unroll
        for (int e4 = 0; e4 < 16; ++e4) {
            float4 a  = *(const float4*)&kvr[cl * 68 + 4 * e4];
            float4 wv = *(const float4*)&wln_s[d * 68 + 4 * e4];
            s += a.x * wv.x + a.y * wv.y + a.z * wv.z + a.w * wv.w;
        }
        kvw_t[(size_t)b * 4096 + d * 64 + c0 + cl] = f2bf(s * inv_k[cl]);
    }
}

// ---------------- K3: per n-tile of 64: coalesced x staging; MFMA q|o GEMM; q stats;
// q2@kvw MFMA; transposed store. Staging LDS reused for the output transpose.
__global__ __launch_bounds__(256) void k3_out(const float* __restrict__ x,
        const u16* __restrict__ w_q_bf, const u16* __restrict__ wvln_bf,
        const float* __restrict__ b_qkv, const float* __restrict__ bias2,
        const u16* __restrict__ kvw_t, float* __restrict__ out) {
    __shared__ float xo[64 * STO];  // phase 1: x tile fp32 (stride SXS); phase 2: ot (stride STO)
    __shared__ u16 qt[64 * STK];    // q2^T-ish: [n][c] bf16 (A-operand for GEMM B)
    const int tid = threadIdx.x;
    const int w = tid >> 6, lane = tid & 63, q = lane >> 4, l15 = lane & 15;
    const int b = blockIdx.y;
    const int n0 = blockIdx.x * 64;
    const float* xb = x + (size_t)b * 64 * NN;
    const int sc = tid >> 4, sn = (tid & 15) << 2;

    // ---- stage x tile (coalesced float4)
    #pragma unroll
    for (int i = 0; i < 4; ++i) {
        int c = 16 * i + sc;
        float4 vld = *(const float4*)(xb + (size_t)c * NN + n0 + sn);
        *(float2*)&xo[c * SXS + sn]     = make_float2(vld.x, vld.y);
        *(float2*)&xo[c * SXS + sn + 2] = make_float2(vld.z, vld.w);
    }

    float bias[8];
    #pragma unroll
    for (int t8 = 0; t8 < 4; ++t8) bias[t8] = b_qkv[16 * t8 + l15];
    #pragma unroll
    for (int t8 = 4; t8 < 8; ++t8) bias[t8] = bias2[16 * (t8 - 4) + l15];

    __syncthreads();

    // ---- GEMM A: cols 0..63 = q, 64..127 = x@wvln^T (+bias2)
    f32x4_t accA[8];
    #pragma unroll
    for (int t8 = 0; t8 < 8; ++t8)
        accA[t8] = (f32x4_t){bias[t8], bias[t8], bias[t8], bias[t8]};
    #pragma unroll
    for (int ks = 0; ks < 2; ++ks) {
        union { u16 u[8]; bf16x8_t v; } af;
        #pragma unroll
        for (int j = 0; j < 8; ++j)
            af.u[j] = f2bf(xo[(ks * 32 + q * 8 + j) * SXS + 16 * w + l15]);
        #pragma unroll
        for (int t8 = 0; t8 < 8; ++t8) {
            const u16* wp = (t8 < 4) ? (w_q_bf + (16 * t8 + l15) * 64)
                                     : (wvln_bf + (16 * (t8 - 4) + l15) * 64);
            bf16x8_t bf = *(const bf16x8_t*)(wp + ks * 32 + q * 8);
            accA[t8] = __builtin_amdgcn_mfma_f32_16x16x32_bf16(af.v, bf, accA[t8], 0, 0, 0);
        }
    }
    // ---- q stats: mu, q2s; q2; w_row = 1/max(||q2||, 1e-12*(q2s+eps))
    float mu[4], q2s[4];
    #pragma unroll
    for (int r = 0; r < 4; ++r) {
        float a0 = accA[0][r], a1 = accA[1][r], a2 = accA[2][r], a3 = accA[3][r];
        float s1 = a0 + a1 + a2 + a3;
        float s2 = a0 * a0 + a1 * a1 + a2 * a2 + a3 * a3;
        #pragma unroll
        for (int m = 1; m <= 8; m <<= 1) {
            s1 += __shfl_xor(s1, m, 64);
            s2 += __shfl_xor(s2, m, 64);
        }
        mu[r] = s1 * 0.015625f;
        q2s[r] = s2 - 64.f * mu[r] * mu[r];
    }
    float q2v[4][4];
    float s4[4] = {0.f, 0.f, 0.f, 0.f};
    #pragma unroll
    for (int t4 = 0; t4 < 4; ++t4)
        #pragma unroll
        for (int r = 0; r < 4; ++r) {
            float d = accA[t4][r] - mu[r];
            float v2 = d * d;
            q2v[t4][r] = v2;
            s4[r] += v2 * v2;
        }
    float w_row[4];
    #pragma unroll
    for (int r = 0; r < 4; ++r) {
        float s = s4[r];
        #pragma unroll
        for (int m = 1; m <= 8; m <<= 1) s += __shfl_xor(s, m, 64);
        w_row[r] = 1.f / fmaxf(sqrtf(s), 1e-12f * (q2s[r] + 1e-7f));
    }
    // ---- q2 -> qt LDS ([n][c] bf16)
    #pragma unroll
    for (int t4 = 0; t4 < 4; ++t4)
        #pragma unroll
        for (int r = 0; r < 4; ++r)
            qt[(16 * w + 4 * q + r) * STK + 16 * t4 + l15] = f2bf(q2v[t4][r]);
    __syncthreads();   // after this barrier xo's x-tile is dead -> reuse for ot
    // ---- GEMM B: t2[n][d] = sum_c q2[n][c]*kvw[c][d]
    f32x4_t accB[4];
    #pragma unroll
    for (int dt = 0; dt < 4; ++dt) accB[dt] = (f32x4_t){0.f, 0.f, 0.f, 0.f};
    #pragma unroll
    for (int ks = 0; ks < 2; ++ks) {
        union { bf16x8_t v; uint2 h[2]; } a2;
        const u16* ap = &qt[(16 * w + l15) * STK + ks * 32 + q * 8];
        a2.h[0] = *(const uint2*)ap;
        a2.h[1] = *(const uint2*)(ap + 4);
        #pragma unroll
        for (int dt = 0; dt < 4; ++dt) {
            bf16x8_t bf = *(const bf16x8_t*)(kvw_t + (size_t)b * 4096 + (16 * dt + l15) * 64 + ks * 32 + q * 8);
            accB[dt] = __builtin_amdgcn_mfma_f32_16x16x32_bf16(a2.v, bf, accB[dt], 0, 0, 0);
        }
    }
    // ---- epilogue: out = o + w_row * t2 ; transpose through LDS (xo reused as ot)
    #pragma unroll
    for (int dt = 0; dt < 4; ++dt) {
        #pragma unroll
        for (int rp = 0; rp < 2; ++rp) {
            float o0 = accA[4 + dt][2 * rp] + w_row[2 * rp] * accB[dt][2 * rp];
            float o1 = accA[4 + dt][2 * rp + 1] + w_row[2 * rp + 1] * accB[dt][2 * rp + 1];
            *(float2*)&xo[(16 * dt + l15) * STO + 16 * w + 4 * q + 2 * rp] = make_float2(o0, o1);
        }
    }
    __syncthreads();
    #pragma unroll
    for (int l = 0; l < 4; ++l) {
        int idx = tid + 256 * l;
        int d = idx >> 4, ng = idx & 15;
        *(float4*)(out + ((size_t)(b * 64 + d)) * NN + n0 + 4 * ng) = *(const float4*)&xo[d * STO + 4 * ng];
    }
}

extern "C" void kernel_launch(void* const* d_in, const int* in_sizes, int n_in,
                              void* d_out, int out_size, void* d_ws, size_t ws_size,
                              hipStream_t stream) {
    const float* x     = (const float*)d_in[0];
    const float* w_qkv = (const float*)d_in[1];
    const float* b_qkv = (const float*)d_in[2];
    const float* w_ln  = (const float*)d_in[3];
    const float* b_ln  = (const float*)d_in[4];
    float* out = (float*)d_out;
    char* ws = (char*)d_ws;
    // byte layout (total 12.88 MB, unchanged)
    float* kvu_part = (float*)(ws);                       // 8*96*4096 f32
    float* ksq_part = (float*)(ws + 12582912);            // 8*96*64 f32
    u16*   kvw_t    = (u16*)  (ws + 12779520);            // 8*4096 bf16
    u16*   w_kv_bf  = (u16*)  (ws + 12845056);            // 128*64 bf16
    u16*   w_q_bf   = (u16*)  (ws + 12861440);            // 64*64 bf16
    u16*   wvln_bf  = (u16*)  (ws + 12869632);            // 64*64 bf16
    float* bias2    = (float*)(ws + 12877824);            // 64 f32

    k0_prep<<<dim3(65), dim3(256), 0, stream>>>(w_qkv, b_qkv, w_ln, b_ln,
                                                w_kv_bf, w_q_bf, wvln_bf, bias2);
    k1_kv<<<dim3(G1, 8), dim3(256), 0, stream>>>(x, w_kv_bf, b_qkv, kvu_part, ksq_part);
    k2_kvw<<<dim3(16, 8), dim3(256), 0, stream>>>(kvu_part, ksq_part, w_ln, kvw_t);
    k3_out<<<dim3(1024, 8), dim3(256), 0, stream>>>(x, w_q_bf, wvln_bf, b_qkv, bias2, kvw_t, out);
}

// Round 3
// 305.545 us; speedup vs baseline: 1.3143x; 1.1272x over previous
//
#include <hip/hip_runtime.h>

// ESSAttn bf16-MFMA version. b=8, C=64, H=W=256 (N=65536), fp32 in/out.
// Math (exact refactor of reference):
//   out[b,n,d] = x_col(n)@wvln[d,:] + bias2[d] + w_row[n] * sum_c q2[n,c]*kvw[b][c][d]
//   kvw[c][d]  = inv_k[c] * sum_e kvu[c][e]*w_ln[d][e],  inv_k = 1/(256*max(sqrt(ksq_c),1e-12))
//   kvu[c][e]  = sum_n k2t[n,c]*v[n,e],  ksq_c = sum_n k2t^2
//   k2t = (k-mean_c(k))^2/(k2s+1e-7),  q2 = (q-mean)^2, w_row folds q2 normalizations.
// Round 3: k3 rewritten as persistent multi-tile (G3=192, reg-prefetch pipeline like k1);
// o and t2 GEMMs operand-SWAPPED (A=weights, B=x/q2 frag) so D comes out [d][n]-major and
// the epilogue stores directly from registers (no ot LDS transpose, no 3rd barrier, no
// 8-way-conflict ds_writes). w_row redistributed n-row->n-col lanes via tiny LDS.
// Bitwise-identical output (same MFMA sums, same fp order). k0/k1/k2 unchanged.

typedef unsigned short u16;
typedef unsigned int u32;
typedef short bf16x8_t __attribute__((ext_vector_type(8)));
typedef float f32x4_t __attribute__((ext_vector_type(4)));

#define NN 65536
#define G1 96
#define G3 192   // k3 persistent blocks per batch: 1536 blocks = 6/CU (LDS allows 6)
#define STK 68   // bf16 LDS tile stride (elements)
#define SXS 66   // fp32 x-tile LDS stride (66: frag-read quad offset -> 2-way free)

static __device__ __forceinline__ u16 f2bf(float f) {
    union { float f; u32 u; } v; v.f = f;
    u32 r = v.u + 0x7FFFu + ((v.u >> 16) & 1u);
    return (u16)(r >> 16);
}
static __device__ __forceinline__ u32 pack2(float a, float b) {
    return (u32)f2bf(a) | ((u32)f2bf(b) << 16);
}

// ---------------- K0: cast weights to bf16; wvln = w_ln @ w_v; bias2 = w_ln@b_v + b_ln
__global__ void k0_prep(const float* __restrict__ w_qkv, const float* __restrict__ b_qkv,
                        const float* __restrict__ w_ln, const float* __restrict__ b_ln,
                        u16* __restrict__ w_kv_bf, u16* __restrict__ w_q_bf,
                        u16* __restrict__ wvln_bf, float* __restrict__ bias2) {
    int idx = blockIdx.x * 256 + threadIdx.x;
    if (idx < 8192) {                       // rows 64..191 of w_qkv = [w_k | w_v]
        w_kv_bf[idx] = f2bf(w_qkv[4096 + idx]);
    } else if (idx < 12288) {               // rows 0..63 = w_q
        w_q_bf[idx - 8192] = f2bf(w_qkv[idx - 8192]);
    } else if (idx < 16384) {
        int i = idx - 12288; int d = i >> 6, c = i & 63;
        float s = 0.f;
        #pragma unroll 8
        for (int e = 0; e < 64; ++e)
            s += w_ln[d * 64 + e] * w_qkv[(128 + e) * 64 + c];
        wvln_bf[i] = f2bf(s);
    } else if (idx < 16448) {
        int d = idx - 16384;
        float s = b_ln[d];
        #pragma unroll 8
        for (int e = 0; e < 64; ++e)
            s += w_ln[d * 64 + e] * b_qkv[128 + e];
        bias2[d] = s;
    }
}

// ---------------- K1: per (g,b): loop n-tiles of 64; coalesced x staging + reg prefetch;
// MFMA k|v GEMM; shuffle stats; LDS-transpose k2t,v to bf16; MFMA kvu accumulation;
// flush per-block partials. (unchanged from round 2)
__global__ __launch_bounds__(256) void k1_kv(const float* __restrict__ x,
        const u16* __restrict__ w_kv_bf, const float* __restrict__ b_qkv,
        float* __restrict__ kvu_part, float* __restrict__ ksq_part) {
    __shared__ float xs[64 * SXS]; // x tile fp32: [c][n]
    __shared__ u16 kt[64 * STK];   // k2t^T: [c][n] bf16
    __shared__ u16 vt[64 * STK];   // v^T:   [e][n] bf16
    __shared__ float ksq_red[4][64];
    const int tid = threadIdx.x;
    const int w = tid >> 6, lane = tid & 63, q = lane >> 4, l15 = lane & 15;
    const int b = blockIdx.y, g = blockIdx.x;
    const float* xb = x + (size_t)b * 64 * NN;
    const int sc = tid >> 4;          // staging channel (+16*i), 16 lanes per row
    const int sn = (tid & 15) << 2;   // staging n offset (float4)
    const float* xg = xb + (size_t)sc * NN + sn;

    float bias[8];
    #pragma unroll
    for (int t8 = 0; t8 < 8; ++t8) bias[t8] = b_qkv[64 + 16 * t8 + l15];

    f32x4_t accK[4];
    #pragma unroll
    for (int et = 0; et < 4; ++et) accK[et] = (f32x4_t){0.f, 0.f, 0.f, 0.f};
    float ksq_acc[4] = {0.f, 0.f, 0.f, 0.f};

    // prefetch first tile into registers
    float4 pf[4];
    #pragma unroll
    for (int i = 0; i < 4; ++i)
        pf[i] = *(const float4*)(xg + (size_t)(16 * i) * NN + g * 64);

    for (int t = g; t < NN / 64; t += G1) {
        // ---- commit prefetched x tile to LDS (coalesced source, 2-way-free writes)
        #pragma unroll
        for (int i = 0; i < 4; ++i) {
            int c = 16 * i + sc;
            *(float2*)&xs[c * SXS + sn]     = make_float2(pf[i].x, pf[i].y);
            *(float2*)&xs[c * SXS + sn + 2] = make_float2(pf[i].z, pf[i].w);
        }
        __syncthreads();
        // ---- issue next tile's loads; latency hides under GEMM/stats below
        if (t + G1 < NN / 64) {
            #pragma unroll
            for (int i = 0; i < 4; ++i)
                pf[i] = *(const float4*)(xg + (size_t)(16 * i) * NN + (t + G1) * 64);
        }
        // ---- GEMM A: D[n][dcol], dcol 0..63 = k, 64..127 = v (K = 64 channels)
        f32x4_t accA[8];
        #pragma unroll
        for (int t8 = 0; t8 < 8; ++t8)
            accA[t8] = (f32x4_t){bias[t8], bias[t8], bias[t8], bias[t8]};
        #pragma unroll
        for (int ks = 0; ks < 2; ++ks) {
            // A-frag: x^T[n][c] via transposed LDS reads (balanced 2-way banks)
            union { u16 u[8]; bf16x8_t v; } af;
            #pragma unroll
            for (int j = 0; j < 8; ++j)
                af.u[j] = f2bf(xs[(ks * 32 + q * 8 + j) * SXS + 16 * w + l15]);
            #pragma unroll
            for (int t8 = 0; t8 < 8; ++t8) {
                bf16x8_t bf = *(const bf16x8_t*)(w_kv_bf + (16 * t8 + l15) * 64 + ks * 32 + q * 8);
                accA[t8] = __builtin_amdgcn_mfma_f32_16x16x32_bf16(af.v, bf, accA[t8], 0, 0, 0);
            }
        }
        // ---- k stats per row (row = 4q + r): mean, 1/(k2s+eps) via 16-lane butterflies
        float mu[4], rin[4];
        #pragma unroll
        for (int r = 0; r < 4; ++r) {
            float a0 = accA[0][r], a1 = accA[1][r], a2 = accA[2][r], a3 = accA[3][r];
            float s1 = a0 + a1 + a2 + a3;
            float s2 = a0 * a0 + a1 * a1 + a2 * a2 + a3 * a3;
            #pragma unroll
            for (int m = 1; m <= 8; m <<= 1) {
                s1 += __shfl_xor(s1, m, 64);
                s2 += __shfl_xor(s2, m, 64);
            }
            mu[r] = s1 * 0.015625f;
            rin[r] = 1.f / (s2 - 64.f * mu[r] * mu[r] + 1e-7f);
        }
        // ---- k2t -> kt LDS (bf16), ksq accumulate; v -> vt LDS
        #pragma unroll
        for (int t4 = 0; t4 < 4; ++t4) {
            float t2v[4];
            #pragma unroll
            for (int r = 0; r < 4; ++r) {
                float d = accA[t4][r] - mu[r];
                float t2 = d * d * rin[r];
                t2v[r] = t2;
                ksq_acc[t4] += t2 * t2;
            }
            int base = (16 * t4 + l15) * STK + 16 * w + 4 * q;
            *(u32*)&kt[base] = pack2(t2v[0], t2v[1]);
            *(u32*)&kt[base + 2] = pack2(t2v[2], t2v[3]);
        }
        #pragma unroll
        for (int t4 = 0; t4 < 4; ++t4) {
            int base = (16 * t4 + l15) * STK + 16 * w + 4 * q;
            *(u32*)&vt[base] = pack2(accA[4 + t4][0], accA[4 + t4][1]);
            *(u32*)&vt[base + 2] = pack2(accA[4 + t4][2], accA[4 + t4][3]);
        }
        __syncthreads();
        // ---- kvu: D[c][e] += sum_n k2t[n][c]*v[n][e]; wave w owns c-tile w
        #pragma unroll
        for (int ks2 = 0; ks2 < 2; ++ks2) {
            union { bf16x8_t v; uint2 h[2]; } a2;
            const u16* ap = &kt[(16 * w + l15) * STK + ks2 * 32 + q * 8];
            a2.h[0] = *(const uint2*)ap;
            a2.h[1] = *(const uint2*)(ap + 4);
            #pragma unroll
            for (int et = 0; et < 4; ++et) {
                union { bf16x8_t v; uint2 h[2]; } b2;
                const u16* bp = &vt[(16 * et + l15) * STK + ks2 * 32 + q * 8];
                b2.h[0] = *(const uint2*)bp;
                b2.h[1] = *(const uint2*)(bp + 4);
                accK[et] = __builtin_amdgcn_mfma_f32_16x16x32_bf16(a2.v, b2.v, accK[et], 0, 0, 0);
            }
        }
        __syncthreads();
    }
    // ---- flush partials
    float* kp = kvu_part + (size_t)(b * G1 + g) * 4096;
    #pragma unroll
    for (int et = 0; et < 4; ++et)
        #pragma unroll
        for (int r = 0; r < 4; ++r)
            kp[(16 * w + 4 * q + r) * 64 + 16 * et + l15] = accK[et][r];
    #pragma unroll
    for (int t4 = 0; t4 < 4; ++t4) {
        float v = ksq_acc[t4];
        v += __shfl_xor(v, 16, 64);
        v += __shfl_xor(v, 32, 64);
        if (q == 0) ksq_red[w][16 * t4 + l15] = v;
    }
    __syncthreads();
    if (tid < 64)
        ksq_part[(size_t)(b * G1 + g) * 64 + tid] =
            ksq_red[0][tid] + ksq_red[1][tid] + ksq_red[2][tid] + ksq_red[3][tid];
}

// ---------------- K2: reduce partials over g; kvw_t[b][d][c] = bf16(inv_k[c]*sum_e kvu[c][e]*w_ln[d][e])
// (unchanged from round 2)
__global__ __launch_bounds__(256) void k2_kvw(const float* __restrict__ kvu_part,
        const float* __restrict__ ksq_part, const float* __restrict__ w_ln,
        u16* __restrict__ kvw_t) {
    __shared__ float wln_s[64 * 68];
    __shared__ float kvr[4 * 68];
    __shared__ float ksq_r[64];
    __shared__ float inv_k[4];
    const int tid = threadIdx.x;
    const int c0 = blockIdx.x * 4, b = blockIdx.y;
    #pragma unroll
    for (int lidx = 0; lidx < 16; ++lidx) {
        int idx = tid + 256 * lidx;
        wln_s[(idx >> 6) * 68 + (idx & 63)] = w_ln[idx];
    }
    {   // thread (cl = tid>>6, e = tid&63): sum kvu over g, 8 concurrent chains
        const int cl = tid >> 6, e = tid & 63;
        const float* p = kvu_part + (size_t)b * G1 * 4096 + (c0 + cl) * 64 + e;
        float s[8];
        #pragma unroll
        for (int k = 0; k < 8; ++k) s[k] = 0.f;
        for (int g = 0; g < G1; g += 8) {
            #pragma unroll
            for (int k = 0; k < 8; ++k) s[k] += p[(size_t)(g + k) * 4096];
        }
        kvr[cl * 68 + e] = ((s[0] + s[1]) + (s[2] + s[3])) + ((s[4] + s[5]) + (s[6] + s[7]));
    }
    if (tid < 64) {  // ksq reduce spread over 16 g-partials x 4 c
        const int cl = tid & 3, gp = tid >> 2;
        float s = 0.f;
        #pragma unroll
        for (int k = 0; k < 6; ++k)
            s += ksq_part[(size_t)(b * G1 + gp + 16 * k) * 64 + c0 + cl];
        ksq_r[tid] = s;
    }
    __syncthreads();
    if (tid < 4) {
        float s = 0.f;
        #pragma unroll
        for (int gp = 0; gp < 16; ++gp) s += ksq_r[gp * 4 + tid];
        inv_k[tid] = 1.f / (fmaxf(sqrtf(s), 1e-12f) * 256.f);
    }
    __syncthreads();
    {   // thread (d = tid>>2, cl = tid&3): 64-wide dot, vectorized
        const int d = tid >> 2, cl = tid & 3;
        float s = 0.f;
        #pragma unroll
        for (int e4 = 0; e4 < 16; ++e4) {
            float4 a  = *(const float4*)&kvr[cl * 68 + 4 * e4];
            float4 wv = *(const float4*)&wln_s[d * 68 + 4 * e4];
            s += a.x * wv.x + a.y * wv.y + a.z * wv.z + a.w * wv.w;
        }
        kvw_t[(size_t)b * 4096 + d * 64 + c0 + cl] = f2bf(s * inv_k[cl]);
    }
}

// ---------------- K3: persistent multi-tile; reg-prefetch pipeline; operand-swapped
// d-major o/t2 GEMMs; direct register->global stores (no output LDS transpose).
__global__ __launch_bounds__(256) void k3_out(const float* __restrict__ x,
        const u16* __restrict__ w_q_bf, const u16* __restrict__ wvln_bf,
        const float* __restrict__ b_qkv, const float* __restrict__ bias2,
        const u16* __restrict__ kvw_t, float* __restrict__ out) {
    __shared__ float xs[64 * SXS];   // x tile fp32: [c][n]
    __shared__ u16 qt[64 * STK];     // q2: [n][c] bf16
    __shared__ float wrow_s[4][16];  // per-wave w_row redistribution (n-row -> n-col lanes)
    const int tid = threadIdx.x;
    const int w = tid >> 6, lane = tid & 63, q = lane >> 4, l15 = lane & 15;
    const int b = blockIdx.y, g = blockIdx.x;
    const float* xb = x + (size_t)b * 64 * NN;
    const int sc = tid >> 4, sn = (tid & 15) << 2;
    const float* xg = xb + (size_t)sc * NN + sn;
    const u16* kvb = kvw_t + (size_t)b * 4096;

    float biasQ[4];
    #pragma unroll
    for (int t4 = 0; t4 < 4; ++t4) biasQ[t4] = b_qkv[16 * t4 + l15];
    float biasO[4][4];   // bias2[d] for d = 16*dt + 4*q + r (d-major accO init)
    #pragma unroll
    for (int dt = 0; dt < 4; ++dt)
        #pragma unroll
        for (int r = 0; r < 4; ++r) biasO[dt][r] = bias2[16 * dt + 4 * q + r];

    // prefetch first tile into registers
    float4 pf[4];
    #pragma unroll
    for (int i = 0; i < 4; ++i)
        pf[i] = *(const float4*)(xg + (size_t)(16 * i) * NN + g * 64);

    for (int t = g; t < NN / 64; t += G3) {
        const int n0 = t * 64;
        // ---- commit prefetched x tile to LDS
        #pragma unroll
        for (int i = 0; i < 4; ++i) {
            int c = 16 * i + sc;
            *(float2*)&xs[c * SXS + sn]     = make_float2(pf[i].x, pf[i].y);
            *(float2*)&xs[c * SXS + sn + 2] = make_float2(pf[i].z, pf[i].w);
        }
        __syncthreads();   // B1: xs ready; also all waves done reading qt of prev tile
        // ---- issue next tile's loads; latency hides under the compute below
        if (t + G3 < NN / 64) {
            #pragma unroll
            for (int i = 0; i < 4; ++i)
                pf[i] = *(const float4*)(xg + (size_t)(16 * i) * NN + (t + G3) * 64);
        }
        // ---- GEMM A: accQ = q (n-major, for stats); accO = o = x@wvln^T + bias2 (d-major)
        f32x4_t accQ[4], accO[4];
        #pragma unroll
        for (int t4 = 0; t4 < 4; ++t4)
            accQ[t4] = (f32x4_t){biasQ[t4], biasQ[t4], biasQ[t4], biasQ[t4]};
        #pragma unroll
        for (int dt = 0; dt < 4; ++dt)
            accO[dt] = (f32x4_t){biasO[dt][0], biasO[dt][1], biasO[dt][2], biasO[dt][3]};
        #pragma unroll
        for (int ks = 0; ks < 2; ++ks) {
            union { u16 u[8]; bf16x8_t v; } af;   // x^T[n][c] frag
            #pragma unroll
            for (int j = 0; j < 8; ++j)
                af.u[j] = f2bf(xs[(ks * 32 + q * 8 + j) * SXS + 16 * w + l15]);
            #pragma unroll
            for (int t4 = 0; t4 < 4; ++t4) {
                bf16x8_t bq = *(const bf16x8_t*)(w_q_bf + (16 * t4 + l15) * 64 + ks * 32 + q * 8);
                accQ[t4] = __builtin_amdgcn_mfma_f32_16x16x32_bf16(af.v, bq, accQ[t4], 0, 0, 0);
            }
            #pragma unroll
            for (int dt = 0; dt < 4; ++dt) {
                bf16x8_t aw = *(const bf16x8_t*)(wvln_bf + (16 * dt + l15) * 64 + ks * 32 + q * 8);
                accO[dt] = __builtin_amdgcn_mfma_f32_16x16x32_bf16(aw, af.v, accO[dt], 0, 0, 0);
            }
        }
        // ---- q stats: mu, q2s; q2; w_row = 1/max(||q2||, 1e-12*(q2s+eps))
        float mu[4], q2s[4];
        #pragma unroll
        for (int r = 0; r < 4; ++r) {
            float a0 = accQ[0][r], a1 = accQ[1][r], a2 = accQ[2][r], a3 = accQ[3][r];
            float s1 = a0 + a1 + a2 + a3;
            float s2 = a0 * a0 + a1 * a1 + a2 * a2 + a3 * a3;
            #pragma unroll
            for (int m = 1; m <= 8; m <<= 1) {
                s1 += __shfl_xor(s1, m, 64);
                s2 += __shfl_xor(s2, m, 64);
            }
            mu[r] = s1 * 0.015625f;
            q2s[r] = s2 - 64.f * mu[r] * mu[r];
        }
        float q2v[4][4];
        float s4[4] = {0.f, 0.f, 0.f, 0.f};
        #pragma unroll
        for (int t4 = 0; t4 < 4; ++t4)
            #pragma unroll
            for (int r = 0; r < 4; ++r) {
                float d = accQ[t4][r] - mu[r];
                float v2 = d * d;
                q2v[t4][r] = v2;
                s4[r] += v2 * v2;
            }
        float w_row[4];
        #pragma unroll
        for (int r = 0; r < 4; ++r) {
            float s = s4[r];
            #pragma unroll
            for (int m = 1; m <= 8; m <<= 1) s += __shfl_xor(s, m, 64);
            w_row[r] = 1.f / fmaxf(sqrtf(s), 1e-12f * (q2s[r] + 1e-7f));
        }
        // ---- redistribute w_row: row n=16w+4q+r (uniform over l15) -> lane col l15
        if (l15 == 0) {
            #pragma unroll
            for (int r = 0; r < 4; ++r) wrow_s[w][4 * q + r] = w_row[r];
        }
        // ---- q2 -> qt LDS ([n][c] bf16)
        #pragma unroll
        for (int t4 = 0; t4 < 4; ++t4)
            #pragma unroll
            for (int r = 0; r < 4; ++r)
                qt[(16 * w + 4 * q + r) * STK + 16 * t4 + l15] = f2bf(q2v[t4][r]);
        __syncthreads();   // B2: qt + wrow_s ready
        // ---- GEMM B (d-major): t2[d][n] = sum_c kvw[d][c]^T-frag * q2[n][c]
        float wr = wrow_s[w][l15];
        f32x4_t accB[4];
        #pragma unroll
        for (int dt = 0; dt < 4; ++dt) accB[dt] = (f32x4_t){0.f, 0.f, 0.f, 0.f};
        #pragma unroll
        for (int ks = 0; ks < 2; ++ks) {
            union { bf16x8_t v; uint2 h[2]; } b2;   // q2[n][c] frag as B-operand
            const u16* bp = &qt[(16 * w + l15) * STK + ks * 32 + q * 8];
            b2.h[0] = *(const uint2*)bp;
            b2.h[1] = *(const uint2*)(bp + 4);
            #pragma unroll
            for (int dt = 0; dt < 4; ++dt) {
                bf16x8_t ak = *(const bf16x8_t*)(kvb + (16 * dt + l15) * 64 + ks * 32 + q * 8);
                accB[dt] = __builtin_amdgcn_mfma_f32_16x16x32_bf16(ak, b2.v, accB[dt], 0, 0, 0);
            }
        }
        // ---- epilogue: out[d][n] = o + w_row[n]*t2, direct register stores
        // lane (q,l15), reg (dt,r): d = 16*dt + 4*q + r, n = n0 + 16*w + l15
        #pragma unroll
        for (int dt = 0; dt < 4; ++dt) {
            float* op = out + ((size_t)(b * 64 + 16 * dt + 4 * q)) * NN + n0 + 16 * w + l15;
            #pragma unroll
            for (int r = 0; r < 4; ++r)
                op[(size_t)r * NN] = accO[dt][r] + wr * accB[dt][r];
        }
    }
}

extern "C" void kernel_launch(void* const* d_in, const int* in_sizes, int n_in,
                              void* d_out, int out_size, void* d_ws, size_t ws_size,
                              hipStream_t stream) {
    const float* x     = (const float*)d_in[0];
    const float* w_qkv = (const float*)d_in[1];
    const float* b_qkv = (const float*)d_in[2];
    const float* w_ln  = (const float*)d_in[3];
    const float* b_ln  = (const float*)d_in[4];
    float* out = (float*)d_out;
    char* ws = (char*)d_ws;
    // byte layout (total 12.88 MB, unchanged)
    float* kvu_part = (float*)(ws);                       // 8*96*4096 f32
    float* ksq_part = (float*)(ws + 12582912);            // 8*96*64 f32
    u16*   kvw_t    = (u16*)  (ws + 12779520);            // 8*4096 bf16
    u16*   w_kv_bf  = (u16*)  (ws + 12845056);            // 128*64 bf16
    u16*   w_q_bf   = (u16*)  (ws + 12861440);            // 64*64 bf16
    u16*   wvln_bf  = (u16*)  (ws + 12869632);            // 64*64 bf16
    float* bias2    = (float*)(ws + 12877824);            // 64 f32

    k0_prep<<<dim3(65), dim3(256), 0, stream>>>(w_qkv, b_qkv, w_ln, b_ln,
                                                w_kv_bf, w_q_bf, wvln_bf, bias2);
    k1_kv<<<dim3(G1, 8), dim3(256), 0, stream>>>(x, w_kv_bf, b_qkv, kvu_part, ksq_part);
    k2_kvw<<<dim3(16, 8), dim3(256), 0, stream>>>(kvu_part, ksq_part, w_ln, kvw_t);
    k3_out<<<dim3(G3, 8), dim3(256), 0, stream>>>(x, w_q_bf, wvln_bf, b_qkv, bias2, kvw_t, out);
}